// Round 1
// baseline (110.988 us; speedup 1.0000x reference)
//
#include <hip/hip_runtime.h>

typedef unsigned short u16;
typedef unsigned int u32;
typedef __bf16 b16x8 __attribute__((ext_vector_type(8)));
typedef float f32x16 __attribute__((ext_vector_type(16)));

#define SEQ   16384
#define DM    2048
#define KT    50
#define NST   48
#define NSP   49

// involution: swap rows 4-7 <-> 8-11 within each 16-block
__device__ __forceinline__ int perm64(int g){
  int q = (g>>2)&3;
  return (q==1 || q==2) ? (g^12) : g;
}
__device__ __forceinline__ u16 bfb(float f){
  __bf16 b = (__bf16)f;
  return __builtin_bit_cast(u16, b);
}
__device__ __forceinline__ int pk2(float a, float b){
  return (int)((u32)bfb(a) | ((u32)bfb(b) << 16));
}
__device__ __forceinline__ b16x8 cast8(int4 v){ return __builtin_bit_cast(b16x8, v); }

__device__ __forceinline__ f32x16 mfma_(b16x8 a, b16x8 b, f32x16 c){
  return __builtin_amdgcn_mfma_f32_32x32x16_bf16(a, b, c, 0, 0, 0);
}

// acc = A * B   (64x64x64, A-frags [mi][kt], B-frags [kt][ni])
__device__ __forceinline__ void mm64(const b16x8 A[2][4], const b16x8 B[4][2], f32x16 acc[2][2]){
#pragma unroll
  for (int mi=0; mi<2; ++mi)
#pragma unroll
    for (int ni=0; ni<2; ++ni){
      f32x16 a;
#pragma unroll
      for (int q=0;q<16;q++) a[q] = 0.0f;
#pragma unroll
      for (int kt=0; kt<4; ++kt) a = mfma_(A[mi][kt], B[kt][ni], a);
      acc[mi][ni] = a;
    }
}

// acc (C/D layout) -> B-frags of the next matmul. With the Pi row-permutation
// convention this is exactly: B-frag[kb] elem r  <-  acc[kb>>1][ni][8*(kb&1)+r]
// (derived & index-checked: repack implements B_phys = Pi * ACC, all in-lane).
__device__ __forceinline__ void repack(const f32x16 acc[2][2], b16x8 B[4][2]){
#pragma unroll
  for (int kb=0; kb<4; ++kb){
    const int mi = kb>>1, t = kb&1;
#pragma unroll
    for (int ni=0; ni<2; ++ni){
      int4 dw;
      dw.x = pk2(acc[mi][ni][8*t+0], acc[mi][ni][8*t+1]);
      dw.y = pk2(acc[mi][ni][8*t+2], acc[mi][ni][8*t+3]);
      dw.z = pk2(acc[mi][ni][8*t+4], acc[mi][ni][8*t+5]);
      dw.w = pk2(acc[mi][ni][8*t+6], acc[mi][ni][8*t+7]);
      B[kb][ni] = cast8(dw);
    }
  }
}

// B-frags of identity (PERM=0) or of the Pi permutation matrix (PERM=1)
template<int PERM>
__device__ __forceinline__ void ident_frags(b16x8 B[4][2], int lane){
  const int h = lane>>5, j0 = lane&31;
#pragma unroll
  for (int kt=0; kt<4; ++kt)
#pragma unroll
    for (int ni=0; ni<2; ++ni){
      const int col = j0 + 32*ni;
      int d[4];
#pragma unroll
      for (int dd=0; dd<4; ++dd){
        int r0 = 16*kt + 8*h + 2*dd, r1 = r0 + 1;
        int p0 = PERM ? perm64(r0) : r0;
        int p1 = PERM ? perm64(r1) : r1;
        d[dd] = (int)((p0==col ? 0x3F80u : 0u) | ((p1==col ? 0x3F80u : 0u) << 16));
      }
      int4 v; v.x=d[0]; v.y=d[1]; v.z=d[2]; v.w=d[3];
      B[kt][ni] = cast8(v);
    }
}

__device__ __forceinline__ float acc_wave_max(const f32x16 acc[2][2]){
  float m = 0.0f;
#pragma unroll
  for (int mi=0;mi<2;mi++)
#pragma unroll
    for (int ni=0;ni<2;ni++)
#pragma unroll
      for (int q=0;q<16;q++) m = fmaxf(m, acc[mi][ni][q]);
#pragma unroll
  for (int o=32;o>=1;o>>=1) m = fmaxf(m, __shfl_xor(m, o, 64));
  return m;
}

// store acc*inv as bf16 matrix; col index always permuted (S = Q*Pi convention),
// row index permuted iff PROW (scan acc = Pi*R).  LDS variant XOR-swizzles cols.
template<int PROW>
__device__ __forceinline__ void store_mat_lds(u16* mat, const f32x16 acc[2][2], float inv, int lane){
  const int h = lane>>5, j0 = lane&31;
#pragma unroll
  for (int mi=0;mi<2;mi++)
#pragma unroll
    for (int ni=0;ni<2;ni++)
#pragma unroll
      for (int r=0;r<16;r++){
        int gp = 32*mi + (r&3) + 8*(r>>2) + 4*h;
        int a = PROW ? perm64(gp) : gp;
        int b = perm64(32*ni + j0);
        mat[a*64 + (b ^ ((a&7)<<3))] = bfb(acc[mi][ni][r]*inv);
      }
}
template<int PROW>
__device__ __forceinline__ void store_mat_glob(u16* mat, const f32x16 acc[2][2], float inv, int lane){
  const int h = lane>>5, j0 = lane&31;
#pragma unroll
  for (int mi=0;mi<2;mi++)
#pragma unroll
    for (int ni=0;ni<2;ni++)
#pragma unroll
      for (int r=0;r<16;r++){
        int gp = 32*mi + (r&3) + 8*(r>>2) + 4*h;
        int a = PROW ? perm64(gp) : gp;
        int b = perm64(32*ni + j0);
        mat[a*64 + b] = bfb(acc[mi][ni][r]*inv);
      }
}
__device__ __forceinline__ void load_afrag_lds(const u16* mat, b16x8 A[2][4], int lane){
  const int h = lane>>5, i0 = lane&31;
#pragma unroll
  for (int mi=0;mi<2;mi++)
#pragma unroll
    for (int kt=0;kt<4;kt++){
      int i = 32*mi + i0;
      int cb = (16*kt + 8*h) ^ ((i&7)<<3);
      A[mi][kt] = cast8(*(const int4*)(mat + i*64 + cb));
    }
}
__device__ __forceinline__ void load_afrag_glob(const u16* mat, b16x8 A[2][4], int lane){
  const int h = lane>>5, i0 = lane&31;
#pragma unroll
  for (int mi=0;mi<2;mi++)
#pragma unroll
    for (int kt=0;kt<4;kt++){
      int i = 32*mi + i0;
      A[mi][kt] = cast8(*(const int4*)(mat + i*64 + 16*kt + 8*h));
    }
}

// ---------------- kernel 1: prep (Wp bf16 padded, E' = Pi*exp(T) padded) -----
__global__ void k_prep(const float* __restrict__ W, const float* __restrict__ T,
                       u16* __restrict__ Wp, u16* __restrict__ E){
  int tid = blockIdx.x*256 + threadIdx.x;
  int n = gridDim.x*256;
  for (int idx = tid; idx < 64*DM; idx += n){
    int r = idx >> 11, d = idx & 2047;
    Wp[idx] = (r < KT) ? bfb(W[r*DM + d]) : (u16)0;
  }
  for (int idx = tid; idx < 64*64; idx += n){
    int a = idx >> 6, b = idx & 63;
    int pa = perm64(a);
    E[idx] = (pa < KT && b < KT) ? bfb(__expf(T[pa*50 + b])) : (u16)0;
  }
}

// ---------------- kernel 2: emission GEMM + row-max shift + gold emissions ---
__global__ __launch_bounds__(256, 2) void k_gemm(const float* __restrict__ in,
      const u16* __restrict__ Wp, const float* __restrict__ bias,
      const int* __restrict__ tags, float* __restrict__ feats, float* __restrict__ gout){
  const int w = threadIdx.x>>6, lane = threadIdx.x&63;
  const int h = lane>>5, i0 = lane&31;
  const int blk = blockIdx.x;
  const int row = blk*32 + i0;
  f32x16 acc0, acc1;
#pragma unroll
  for (int q=0;q<16;q++){ acc0[q]=0.f; acc1[q]=0.f; }
  const float* pa  = in + (size_t)row*DM + w*512 + 8*h;
  const u16*   pb0 = Wp + (size_t)i0*DM + w*512 + 8*h;
  const u16*   pb1 = Wp + (size_t)(i0+32)*DM + w*512 + 8*h;
#pragma unroll 4
  for (int s=0;s<32;s++){
    float4 fa = *(const float4*)(pa + s*16);
    float4 fb = *(const float4*)(pa + s*16 + 4);
    b16x8 av;
    av[0]=(__bf16)fa.x; av[1]=(__bf16)fa.y; av[2]=(__bf16)fa.z; av[3]=(__bf16)fa.w;
    av[4]=(__bf16)fb.x; av[5]=(__bf16)fb.y; av[6]=(__bf16)fb.z; av[7]=(__bf16)fb.w;
    b16x8 b0 = cast8(*(const int4*)(pb0 + s*16));
    b16x8 b1 = cast8(*(const int4*)(pb1 + s*16));
    acc0 = mfma_(av, b0, acc0);
    acc1 = mfma_(av, b1, acc1);
  }
  __shared__ float planes[4][32][64];
#pragma unroll
  for (int r=0;r<16;r++){
    int g = (r&3) + 8*(r>>2) + 4*h;
    planes[w][g][i0]    = acc0[r];
    planes[w][g][i0+32] = acc1[r];
  }
  __syncthreads();
  __shared__ float tile[32][66];
  for (int cidx = threadIdx.x; cidx < 2048; cidx += 256){
    int g = cidx>>6, c = cidx&63;
    float v = planes[0][g][c]+planes[1][g][c]+planes[2][g][c]+planes[3][g][c];
    tile[g][c] = (c<KT) ? (v + bias[c]) : -1e4f;
  }
  __syncthreads();
  __shared__ float mrow[32];
  if (threadIdx.x < 32){
    int g = threadIdx.x;
    float mx = -1e30f;
    for (int c=0;c<KT;c++) mx = fmaxf(mx, tile[g][c]);
    mrow[g] = mx;
    int t = blk*32 + g;
    gout[t] = tile[g][tags[t]] - mx;
  }
  __syncthreads();
  for (int cidx = threadIdx.x; cidx < 2048; cidx += 256){
    int g = cidx>>6, c = cidx&63;
    feats[(size_t)(blk*32+g)*64 + c] = (c<KT) ? (tile[g][c] - mrow[g]) : -1e4f;
  }
}

// ---------------- kernel 3: chunked scan (8 steps/wave) + in-block 8->1 ------
__global__ __launch_bounds__(512, 2) void k_scan(const float* __restrict__ feats,
        const u16* __restrict__ Emat, u16* __restrict__ M1, float* __restrict__ S1){
  const int w = threadIdx.x >> 6, lane = threadIdx.x & 63;
  const int h = lane>>5;
  const int blk = blockIdx.x;
  const int t0 = (blk*8 + w)*8;
  __shared__ __align__(16) float u_lds[8][64];
  __shared__ __align__(16) u16 mats[8][4096];
  __shared__ float logs[8];

  b16x8 Af[2][4];
  load_afrag_glob(Emat, Af, lane);
  b16x8 Bf[4][2];
  ident_frags<0>(Bf, lane);
  const int pl = perm64(lane);
  float x = feats[(size_t)t0*64 + pl];
  f32x16 acc[2][2];
#pragma unroll
  for (int s=0;s<8;s++){
    u_lds[w][lane] = __expf(x);
    if (s<7) x = feats[(size_t)(t0+s+1)*64 + pl];
    mm64(Af, Bf, acc);
    float uu0[16], uu1[16];
#pragma unroll
    for (int k2=0;k2<4;k2++){
      float4 v0 = *(const float4*)&u_lds[w][      8*k2 + 4*h];
      float4 v1 = *(const float4*)&u_lds[w][32 +  8*k2 + 4*h];
      uu0[4*k2+0]=v0.x; uu0[4*k2+1]=v0.y; uu0[4*k2+2]=v0.z; uu0[4*k2+3]=v0.w;
      uu1[4*k2+0]=v1.x; uu1[4*k2+1]=v1.y; uu1[4*k2+2]=v1.z; uu1[4*k2+3]=v1.w;
    }
#pragma unroll
    for (int ni=0;ni<2;ni++)
#pragma unroll
      for (int r=0;r<16;r++){
        acc[0][ni][r] *= uu0[r];
        acc[1][ni][r] *= uu1[r];
      }
    repack(acc, Bf);
  }
  float m = acc_wave_max(acc);
  float inv = 1.0f/m;
  store_mat_lds<1>(mats[w], acc, inv, lane);
  if (lane==0) logs[w] = __logf(m);
  __syncthreads();
  if (w==0){
    float slog = logs[0]+logs[1]+logs[2]+logs[3]+logs[4]+logs[5]+logs[6]+logs[7];
    b16x8 Bc[4][2]; ident_frags<1>(Bc, lane);
    f32x16 a2[2][2];
#pragma unroll 1
    for (int m8=0;m8<8;m8++){
      b16x8 Am[2][4];
      load_afrag_lds(mats[m8], Am, lane);
      mm64(Am, Bc, a2);
      repack(a2, Bc);
    }
    float m2 = acc_wave_max(a2);
    slog += __logf(m2);
    store_mat_glob<0>(M1 + (size_t)blk*4096, a2, 1.0f/m2, lane);
    if (lane==0) S1[blk] = slog;
  }
}

// ---------------- kernel 4: combine 8 matrices -> 1 (256 -> 32) --------------
__global__ __launch_bounds__(64) void k_comb8(const u16* __restrict__ Min, const float* __restrict__ Sin,
      u16* __restrict__ Mout, float* __restrict__ Sout){
  const int lane = threadIdx.x & 63;
  const int blk = blockIdx.x;
  b16x8 Bc[4][2]; ident_frags<1>(Bc, lane);
  f32x16 a2[2][2];
  float slog = 0.f;
#pragma unroll 1
  for (int m=0;m<8;m++){
    b16x8 Am[2][4];
    load_afrag_glob(Min + (size_t)(blk*8+m)*4096, Am, lane);
    slog += Sin[blk*8+m];
    mm64(Am, Bc, a2);
    repack(a2, Bc);
  }
  float mx = acc_wave_max(a2);
  slog += __logf(mx);
  store_mat_glob<0>(Mout + (size_t)blk*4096, a2, 1.0f/mx, lane);
  if (lane==0) Sout[blk] = slog;
}

// ---------------- kernel 5: final 32 -> 1, LSE, gold, output -----------------
__global__ __launch_bounds__(512, 2) void k_final(const u16* __restrict__ M2, const float* __restrict__ S2,
      const float* __restrict__ T, const int* __restrict__ tags,
      const float* __restrict__ gvec, float* __restrict__ out){
  const int w = threadIdx.x>>6, lane = threadIdx.x&63;
  __shared__ __align__(16) u16 mats[8][4096];
  __shared__ float logs[8];
  __shared__ float alpha[64];
  __shared__ float red[512];
  __shared__ float slog_sh;
  {
    b16x8 Bc[4][2]; ident_frags<1>(Bc, lane);
    f32x16 a2[2][2];
    float sl = 0.f;
#pragma unroll 1
    for (int m=0;m<4;m++){
      b16x8 Am[2][4];
      load_afrag_glob(M2 + (size_t)(w*4+m)*4096, Am, lane);
      sl += S2[w*4+m];
      mm64(Am, Bc, a2);
      repack(a2, Bc);
    }
    float mx = acc_wave_max(a2);
    sl += __logf(mx);
    store_mat_lds<0>(mats[w], a2, 1.0f/mx, lane);
    if (lane==0) logs[w] = sl;
  }
  __syncthreads();
  if (w==0){
    b16x8 Bc[4][2]; ident_frags<1>(Bc, lane);
    f32x16 a2[2][2];
#pragma unroll 1
    for (int m=0;m<8;m++){
      b16x8 Am[2][4];
      load_afrag_lds(mats[m], Am, lane);
      mm64(Am, Bc, a2);
      repack(a2, Bc);
    }
    float sl = logs[0]+logs[1]+logs[2]+logs[3]+logs[4]+logs[5]+logs[6]+logs[7];
    if ((lane&31)==16){   // column START=48 lives in lanes 16 / 48 (ni=1)
      const int h = lane>>5;
#pragma unroll
      for (int mi=0;mi<2;mi++)
#pragma unroll
        for (int r=0;r<16;r++){
          int gp = 32*mi + (r&3) + 8*(r>>2) + 4*h;
          alpha[gp] = a2[mi][1][r];
        }
    }
    if (lane==0) slog_sh = sl;
  }
  // gold score (deterministic tree reduction)
  float part = 0.f;
  for (int t = threadIdx.x; t < SEQ; t += 512) part += gvec[t];
  for (int idx = threadIdx.x; idx < SEQ+1; idx += 512){
    int s0 = (idx==0) ? NST : tags[idx-1];
    int s1 = (idx<SEQ) ? tags[idx] : NSP;
    part += T[s1*50 + s0];
  }
  red[threadIdx.x] = part;
  for (int st=256; st>0; st>>=1){
    __syncthreads();
    if (threadIdx.x < st) red[threadIdx.x] += red[threadIdx.x + st];
  }
  __syncthreads();
  if (threadIdx.x < 64){
    float a = alpha[lane];
    float term = (lane < KT && a > 0.f) ? (__logf(a) + slog_sh + T[NSP*50 + lane]) : -1e30f;
    float tm = term;
#pragma unroll
    for (int o=32;o>=1;o>>=1) tm = fmaxf(tm, __shfl_xor(tm, o, 64));
    float e = __expf(term - tm);
#pragma unroll
    for (int o=32;o>=1;o>>=1) e += __shfl_xor(e, o, 64);
    if (threadIdx.x == 0) out[0] = (tm + __logf(e)) - red[0];
  }
}

extern "C" void kernel_launch(void* const* d_in, const int* in_sizes, int n_in,
                              void* d_out, int out_size, void* d_ws, size_t ws_size,
                              hipStream_t stream) {
  (void)in_sizes; (void)n_in; (void)out_size; (void)ws_size;
  const float* input = (const float*)d_in[0];
  const int*   tags  = (const int*)  d_in[1];
  const float* W     = (const float*)d_in[2];
  const float* bias  = (const float*)d_in[3];
  const float* T     = (const float*)d_in[4];

  char* ws = (char*)d_ws;
  float* feats = (float*)(ws + 0);          // 16384*64*4  = 4194304
  float* gvec  = (float*)(ws + 4194304);    // 16384*4     = 65536
  u16*   Wp    = (u16*)  (ws + 4259840);    // 64*2048*2   = 262144
  u16*   Emat  = (u16*)  (ws + 4521984);    // 64*64*2     = 8192
  u16*   M1    = (u16*)  (ws + 4530176);    // 256*4096*2  = 2097152
  float* S1    = (float*)(ws + 6627328);    // 256*4 -> pad 1024
  u16*   M2    = (u16*)  (ws + 6628352);    // 32*4096*2   = 262144
  float* S2    = (float*)(ws + 6890496);    // 32*4

  k_prep <<<256, 256, 0, stream>>>(W, T, Wp, Emat);
  k_gemm <<<512, 256, 0, stream>>>(input, Wp, bias, tags, feats, gvec);
  k_scan <<<256, 512, 0, stream>>>(feats, Emat, M1, S1);
  k_comb8<<<32,  64,  0, stream>>>(M1, S1, M2, S2);
  k_final<<<1,   512, 0, stream>>>(M2, S2, T, tags, gvec, (float*)d_out);
}